// Round 6
// baseline (494.339 us; speedup 1.0000x reference)
//
#include <hip/hip_runtime.h>
#include <hip/hip_bf16.h>
#include <stdint.h>

typedef __bf16 bf16_t;
typedef __bf16 bf16x8 __attribute__((ext_vector_type(8)));
typedef __bf16 bf16x4 __attribute__((ext_vector_type(4)));
typedef float f32x4 __attribute__((ext_vector_type(4)));
typedef short short4v __attribute__((ext_vector_type(4)));

#define BDIM_B 4
#define TDIM 2048
#define CDIM 1024

// -------- async global->LDS (16B per lane, wave-uniform LDS base + lane*16) -----
__device__ __forceinline__ void gload16(const void* g, void* l) {
  using GP = const __attribute__((address_space(1))) char*;
  using LP = __attribute__((address_space(3))) char*;
  __builtin_amdgcn_global_load_lds((GP)(uintptr_t)g, (LP)(uint32_t)(uintptr_t)l, 16, 0, 0);
}

#define S_BARRIER() asm volatile("s_barrier" ::: "memory")

// ---------------- weight transpose + fp32->bf16 cast:  Wt[n][k] = W[k][n] -------
__global__ __launch_bounds__(256)
void transpose_cast(const float* __restrict__ W, bf16_t* __restrict__ Wt, int K, int N) {
  __shared__ float tile[32][33];
  const int tx = threadIdx.x & 31, ty = threadIdx.x >> 5;  // 32 x 8
  const int n0 = blockIdx.x * 32, k0 = blockIdx.y * 32;
#pragma unroll
  for (int j = 0; j < 32; j += 8)
    tile[ty + j][tx] = W[(size_t)(k0 + ty + j) * N + n0 + tx];
  __syncthreads();
#pragma unroll
  for (int j = 0; j < 32; j += 8)
    Wt[(size_t)(n0 + ty + j) * K + k0 + tx] = (bf16_t)tile[tx][ty + j];
}

// ---------------- V pre-transpose: vT[b][h][d][t] = qkv V-part ------------------
__global__ __launch_bounds__(256)
void transpose_v(const bf16_t* __restrict__ qkv, bf16_t* __restrict__ vT) {
  __shared__ bf16_t tile[64 * 64];
  const int tt = blockIdx.x;  // t0 = tt*64
  const int h = blockIdx.y, b = blockIdx.z;
  const int tid = threadIdx.x;
  const int sr = tid >> 3, sc = tid & 7;
  const bf16_t* src = qkv + (size_t)(b * TDIM) * 3072 + 2048 + h * 64;
#pragma unroll
  for (int p = 0; p < 2; ++p) {
    const int t = p * 32 + sr;
    *(uint4*)(tile + t * 64 + ((sc ^ (t & 7)) * 8)) =
        *(const uint4*)(src + (size_t)(tt * 64 + t) * 3072 + sc * 8);
  }
  __syncthreads();
  const int d = tid >> 2, tq = tid & 3;
  bf16_t* dst = vT + ((size_t)((b * 16 + h) * 64 + d)) * TDIM + tt * 64;
#pragma unroll
  for (int p = 0; p < 2; ++p) {
    union { uint4 u; bf16_t e[8]; } o;
#pragma unroll
    for (int j = 0; j < 8; ++j) {
      const int t = p * 32 + tq * 8 + j;
      o.e[j] = tile[t * 64 + (((d >> 3) ^ (t & 7)) * 8) + (d & 7)];
    }
    *(uint4*)(dst + p * 32 + tq * 8) = o.u;
  }
}

// ---------------- fused LayerNorm (fp32 in) -> bf16 out -------------------------
__global__ __launch_bounds__(256)
void ln_kernel(const float* __restrict__ x, const float* __restrict__ g,
               const float* __restrict__ bta, bf16_t* __restrict__ out) {
  const size_t row = blockIdx.x;
  const int tid = threadIdx.x;
  const float4 v = ((const float4*)(x + row * CDIM))[tid];
  float s = v.x + v.y + v.z + v.w;
#pragma unroll
  for (int off = 1; off < 64; off <<= 1) s += __shfl_xor(s, off);
  __shared__ float r1[4], r2[4];
  const int wv = tid >> 6, lane = tid & 63;
  if (!lane) r1[wv] = s;
  __syncthreads();
  const float mu = (r1[0] + r1[1] + r1[2] + r1[3]) * (1.f / CDIM);
  const float dx = v.x - mu, dy = v.y - mu, dz = v.z - mu, dw = v.w - mu;
  float q = dx * dx + dy * dy + dz * dz + dw * dw;
#pragma unroll
  for (int off = 1; off < 64; off <<= 1) q += __shfl_xor(q, off);
  if (!lane) r2[wv] = q;
  __syncthreads();
  const float var = (r2[0] + r2[1] + r2[2] + r2[3]) * (1.f / CDIM);
  const float rs = rsqrtf(var + 1e-5f);
  const float4 gg = ((const float4*)g)[tid];
  const float4 bb = ((const float4*)bta)[tid];
  bf16x4 o;
  o[0] = (bf16_t)(dx * rs * gg.x + bb.x);
  o[1] = (bf16_t)(dy * rs * gg.y + bb.y);
  o[2] = (bf16_t)(dz * rs * gg.z + bb.z);
  o[3] = (bf16_t)(dw * rs * gg.w + bb.w);
  ((bf16x4*)(out + row * CDIM))[tid] = o;
}

enum { EPI_BF16 = 0, EPI_RESID = 1, EPI_GELU = 2 };

// ---------------- 256x256 8-wave MFMA GEMM, stage-at-top dbuf-2 -----------------
// BM=BN=256, BK=64, 512 threads (8 waves 2x4, wave tile 128x64), 2-buf 128KiB.
// v3 lesson: with 1 block/CU, per-phase counted fences retire loads aged only
// 1-2 phases (~150-450cy) vs ~600-900cy L3/HBM latency -> every fence eats raw
// latency, 4x/tile (163us, 421 TF). Fix = maximize aging: issue ALL 8 prefetch
// loads of tile t+1 at the TOP of tile t (target buffer's readers retired at
// the tile-boundary barrier), then ONE drain at tile end -- each load gets a
// full tile (~620cy) of MFMA to land. Phases keep the m201 bracket
// [ds_reads -> s_barrier -> setprio MFMA-quadrant -> s_barrier] for wave
// alignment; fragment reads split 12/4/8/0 just-in-time per quadrant.
template <int EPI>
__global__ __launch_bounds__(512)
void gemm256(const bf16_t* __restrict__ A, const bf16_t* __restrict__ Bt,
             const float* __restrict__ bias, const float* __restrict__ resid,
             void* __restrict__ outv, int M, int N, int K) {
  __shared__ bf16_t sA[2][256 * 64];
  __shared__ bf16_t sB[2][256 * 64];
  const int tid = threadIdx.x;
  const int lane = tid & 63, wv = tid >> 6;
  const int wm = wv >> 2, wn = wv & 3;
  const int rin = lane & 15, quad = lane >> 4;

  const int nwg = gridDim.x * gridDim.y;
  const int bid = blockIdx.y * gridDim.x + blockIdx.x;
  const int swzb = (bid & 7) * (nwg >> 3) + (bid >> 3);
  const int bx = swzb % gridDim.x, by = swzb / gridDim.x;
  const int m0 = by * 256, n0 = bx * 256;

  const int c8 = (lane & 7) ^ ((lane >> 3) & 7);
  const int aRow = wm * 128 + (wv & 3) * 8 + (lane >> 3);
  const int bRow = wn * 64 + (wv >> 2) * 8 + (lane >> 3);
  const bf16_t* srcA = A + (size_t)(m0 + aRow) * K + c8 * 8;
  const bf16_t* srcB = Bt + (size_t)(n0 + bRow) * K + c8 * 8;
  const int dstA = (wm * 128 + (wv & 3) * 8) * 64;
  const int dstB = (wn * 64 + (wv >> 2) * 8) * 64;

#define STA(buf, r, kk) gload16(srcA + (size_t)(32 * (r)) * K + (kk), (buf) + dstA + 32 * (r) * 64)
#define STB(buf, r, kk) gload16(srcB + (size_t)(16 * (r)) * K + (kk), (buf) + dstB + 16 * (r) * 64)

  const int ck0 = (quad ^ (rin & 7)) * 8;
  const int ck1 = ((4 + quad) ^ (rin & 7)) * 8;
  const int aBase = (wm * 128 + rin) * 64;
  const int bBase = (wn * 64 + rin) * 64;

  f32x4 acc[8][4] = {};
  bf16x8 af[8][2], bfr[4][2];

#define RDA(mi) { af[mi][0] = *(const bf16x8*)(rA + aBase + (mi)*1024 + ck0); \
                  af[mi][1] = *(const bf16x8*)(rA + aBase + (mi)*1024 + ck1); }
#define RDB(ni) { bfr[ni][0] = *(const bf16x8*)(rB + bBase + (ni)*1024 + ck0); \
                  bfr[ni][1] = *(const bf16x8*)(rB + bBase + (ni)*1024 + ck1); }
#define MM(mi, ni) { acc[mi][ni] = __builtin_amdgcn_mfma_f32_16x16x32_bf16(af[mi][0], bfr[ni][0], acc[mi][ni], 0, 0, 0); \
                     acc[mi][ni] = __builtin_amdgcn_mfma_f32_16x16x32_bf16(af[mi][1], bfr[ni][1], acc[mi][ni], 0, 0, 0); }

  const int NT = K >> 6;

  // prologue: stage tile 0, drain, barrier
  STA(sA[0], 0, 0); STA(sA[0], 1, 0); STA(sA[0], 2, 0); STA(sA[0], 3, 0);
  STB(sB[0], 0, 0); STB(sB[0], 1, 0); STB(sB[0], 2, 0); STB(sB[0], 3, 0);
  asm volatile("s_waitcnt vmcnt(0)" ::: "memory");
  S_BARRIER();

  for (int t = 0; t < NT; ++t) {
    const bf16_t* rA = sA[t & 1];
    const bf16_t* rB = sB[t & 1];
    bf16_t* wA = sA[(t & 1) ^ 1];
    bf16_t* wB = sB[(t & 1) ^ 1];
    const int kk = (t + 1 < NT ? t + 1 : t) * 64;  // clamp: stray reload hits dead buffer

    // stage ALL of tile t+1 now -- loads age a full tile before the end drain
    STA(wA, 0, kk); STA(wA, 1, kk); STA(wA, 2, kk); STA(wA, 3, kk);
    STB(wB, 0, kk); STB(wB, 1, kk); STB(wB, 2, kk); STB(wB, 3, kk);

    // ph0: quadrant (mi 0-3, ni 0-1)
    RDA(0) RDA(1) RDA(2) RDA(3) RDB(0) RDB(1)
    S_BARRIER();
    __builtin_amdgcn_s_setprio(1);
    MM(0, 0) MM(0, 1) MM(1, 0) MM(1, 1) MM(2, 0) MM(2, 1) MM(3, 0) MM(3, 1)
    __builtin_amdgcn_s_setprio(0);
    S_BARRIER();

    // ph1: quadrant (mi 0-3, ni 2-3)
    RDB(2) RDB(3)
    S_BARRIER();
    __builtin_amdgcn_s_setprio(1);
    MM(0, 2) MM(0, 3) MM(1, 2) MM(1, 3) MM(2, 2) MM(2, 3) MM(3, 2) MM(3, 3)
    __builtin_amdgcn_s_setprio(0);
    S_BARRIER();

    // ph2: quadrant (mi 4-7, ni 0-1)
    RDA(4) RDA(5) RDA(6) RDA(7)
    S_BARRIER();
    __builtin_amdgcn_s_setprio(1);
    MM(4, 0) MM(4, 1) MM(5, 0) MM(5, 1) MM(6, 0) MM(6, 1) MM(7, 0) MM(7, 1)
    __builtin_amdgcn_s_setprio(0);
    S_BARRIER();

    // ph3: quadrant (mi 4-7, ni 2-3), then single end-of-tile drain
    __builtin_amdgcn_s_setprio(1);
    MM(4, 2) MM(4, 3) MM(5, 2) MM(5, 3) MM(6, 2) MM(6, 3) MM(7, 2) MM(7, 3)
    __builtin_amdgcn_s_setprio(0);
    asm volatile("s_waitcnt vmcnt(0)" ::: "memory");  // tile t+1 resident
    S_BARRIER();
  }

  const int rbase = m0 + wm * 128 + quad * 4;
  const int cbase = n0 + wn * 64 + rin;
#pragma unroll
  for (int mi = 0; mi < 8; ++mi)
#pragma unroll
    for (int ni = 0; ni < 4; ++ni)
#pragma unroll
      for (int r = 0; r < 4; ++r) {
        const int m = rbase + mi * 16 + r;
        const int n = cbase + ni * 16;
        float v = acc[mi][ni][r] + bias[n];
        if (EPI == EPI_RESID) v += resid[(size_t)m * N + n];
        if (EPI == EPI_GELU) v = 0.5f * v * (1.0f + erff(v * 0.7071067811865476f));
        if (EPI == EPI_RESID)
          ((float*)outv)[(size_t)m * N + n] = v;
        else
          ((bf16_t*)outv)[(size_t)m * N + n] = (bf16_t)v;
      }
#undef STA
#undef STB
#undef RDA
#undef RDB
#undef MM
}

// ---------------- 256x128 8-wave ring-3 MFMA GEMM (for N=1024 / qkv grids) ------
template <int EPI>
__global__ __launch_bounds__(512)
void gemm128(const bf16_t* __restrict__ A, const bf16_t* __restrict__ Bt,
             const float* __restrict__ bias, const float* __restrict__ resid,
             void* __restrict__ outv, int M, int N, int K) {
  __shared__ bf16_t sA[3][256 * 64];
  __shared__ bf16_t sB[3][128 * 64];
  const int tid = threadIdx.x;
  const int lane = tid & 63, wv = tid >> 6;
  const int wm = wv >> 1, wn = wv & 1;
  const int rin = lane & 15, quad = lane >> 4;

  const int nwg = gridDim.x * gridDim.y;
  const int bid = blockIdx.y * gridDim.x + blockIdx.x;
  const int swzb = (bid & 7) * (nwg >> 3) + (bid >> 3);
  const int bx = swzb % gridDim.x, by = swzb / gridDim.x;
  const int m0 = by * 256, n0 = bx * 128;

  const int c8 = (lane & 7) ^ ((lane >> 3) & 7);
  const bf16_t* srcA = A + (size_t)(m0 + 8 * wv + (lane >> 3)) * K + c8 * 8;
  const int dstA = (8 * wv) * 64;
  const bf16_t* srcB = Bt + (size_t)(n0 + (wv >> 2) * 64 + (wv & 3) * 8 + (lane >> 3)) * K + c8 * 8;
  const int dstB = ((wv >> 2) * 64 + (wv & 3) * 8) * 64;

#define STA(buf, r, kk) gload16(srcA + (size_t)(64 * (r)) * K + (kk), (buf) + dstA + 64 * (r) * 64)
#define STB(buf, r, kk) gload16(srcB + (size_t)(32 * (r)) * K + (kk), (buf) + dstB + 32 * (r) * 64)

  const int ck0 = (quad ^ (rin & 7)) * 8;
  const int ck1 = ((4 + quad) ^ (rin & 7)) * 8;
  const int aBase = (wm * 64 + rin) * 64;
  const int bBase = (wn * 64 + rin) * 64;

  f32x4 acc[4][4] = {};
  bf16x8 af[4][2], bfr[4][2];

#define RDA(mi) { af[mi][0] = *(const bf16x8*)(rA + aBase + (mi)*1024 + ck0); \
                  af[mi][1] = *(const bf16x8*)(rA + aBase + (mi)*1024 + ck1); }
#define RDB(ni) { bfr[ni][0] = *(const bf16x8*)(rB + bBase + (ni)*1024 + ck0); \
                  bfr[ni][1] = *(const bf16x8*)(rB + bBase + (ni)*1024 + ck1); }
#define MM(mi, ni) { acc[mi][ni] = __builtin_amdgcn_mfma_f32_16x16x32_bf16(af[mi][0], bfr[ni][0], acc[mi][ni], 0, 0, 0); \
                     acc[mi][ni] = __builtin_amdgcn_mfma_f32_16x16x32_bf16(af[mi][1], bfr[ni][1], acc[mi][ni], 0, 0, 0); }

  const int NT = K >> 6;

  STA(sA[0], 0, 0); STA(sA[0], 1, 0); STA(sA[0], 2, 0); STA(sA[0], 3, 0); STB(sB[0], 0, 0);
  STB(sB[0], 1, 0);
  STA(sA[1], 0, 64); STA(sA[1], 1, 64); STA(sA[1], 2, 64); STA(sA[1], 3, 64); STB(sB[1], 0, 64);
  STB(sB[1], 1, 64);
  asm volatile("s_waitcnt vmcnt(7)" ::: "memory");
  S_BARRIER();

  int rb = 0, wb = 2;
  for (int t = 0; t < NT; ++t) {
    const bf16_t* rA = sA[rb];
    const bf16_t* rB = sB[rb];
    bf16_t* wA = sA[wb];
    bf16_t* wB = sB[wb];
    const int kk = (t + 2 < NT ? t + 2 : NT - 1) * 64;

    RDA(0) RDA(1) RDA(2) RDA(3) RDB(0) RDB(1)
    asm volatile("s_waitcnt vmcnt(6)" ::: "memory");
    S_BARRIER();
    STA(wA, 0, kk); STA(wA, 1, kk); STA(wA, 2, kk); STA(wA, 3, kk); STB(wB, 0, kk);
    __builtin_amdgcn_s_setprio(1);
    MM(0, 0) MM(0, 1) MM(1, 0) MM(1, 1) MM(2, 0) MM(2, 1) MM(3, 0) MM(3, 1)
    __builtin_amdgcn_s_setprio(0);

    RDB(2) RDB(3)
    asm volatile("s_waitcnt vmcnt(6)" ::: "memory");
    S_BARRIER();
    STB(wB, 1, kk);
    __builtin_amdgcn_s_setprio(1);
    MM(0, 2) MM(0, 3) MM(1, 2) MM(1, 3) MM(2, 2) MM(2, 3) MM(3, 2) MM(3, 3)
    __builtin_amdgcn_s_setprio(0);

    rb = (rb == 2) ? 0 : rb + 1;
    wb = (wb == 2) ? 0 : wb + 1;
  }
  asm volatile("s_waitcnt vmcnt(0)" ::: "memory");

  const int rbase = m0 + wm * 64 + quad * 4;
  const int cbase = n0 + wn * 64 + rin;
#pragma unroll
  for (int mi = 0; mi < 4; ++mi)
#pragma unroll
    for (int ni = 0; ni < 4; ++ni)
#pragma unroll
      for (int r = 0; r < 4; ++r) {
        const int m = rbase + mi * 16 + r;
        const int n = cbase + ni * 16;
        float v = acc[mi][ni][r] + bias[n];
        if (EPI == EPI_RESID) v += resid[(size_t)m * N + n];
        if (EPI == EPI_GELU) v = 0.5f * v * (1.0f + erff(v * 0.7071067811865476f));
        if (EPI == EPI_RESID)
          ((float*)outv)[(size_t)m * N + n] = v;
        else
          ((bf16_t*)outv)[(size_t)m * N + n] = (bf16_t)v;
      }
#undef STA
#undef STB
#undef RDA
#undef RDB
#undef MM
}

// ---------------- flash attention v4.1, causal, H=16 D=64 ----------------------
__global__ __launch_bounds__(256)
void attn_kernel(const bf16_t* __restrict__ qkv, const bf16_t* __restrict__ vT,
                 bf16_t* __restrict__ y) {
  const int id = blockIdx.x;
  const int bx = id >> 6;
  const int h = id & 15, b = (id >> 4) & 3;
  const int tid = threadIdx.x, lane = tid & 63, wv = tid >> 6;
  const int rin = lane & 15, quad = lane >> 4;

  __shared__ bf16_t K2[2][64 * 64];  // K [t][d], chunk ^ (t&7)
  __shared__ bf16_t V2[2][64 * 64];  // V^T [d][t], chunk ^ (d&7)

  const size_t base3 = (size_t)(b * TDIM) * 3072;
  const bf16_t* Kg = qkv + base3 + 1024 + h * 64;                 // + t*3072
  const bf16_t* Vg = vT + (size_t)((b * 16 + h) * 64) * TDIM;     // + d*2048
  const int sr = tid >> 3, sc = tid & 7;  // staging: row sr(+32), chunk sc
  const int sx = (sc ^ (sr & 7)) * 8;     // pre-swizzled source chunk
  const short4v ones = {(short)0x3F80, (short)0x3F80, (short)0x3F80, (short)0x3F80};

#define STAGE(bi, kt_) { \
    gload16(Kg + (size_t)((kt_) * 64 + sr) * 3072 + sx,      K2[bi] + sr * 64 + sc * 8);        \
    gload16(Kg + (size_t)((kt_) * 64 + 32 + sr) * 3072 + sx, K2[bi] + (32 + sr) * 64 + sc * 8); \
    gload16(Vg + (size_t)sr * TDIM + (kt_) * 64 + sx,        V2[bi] + sr * 64 + sc * 8);        \
    gload16(Vg + (size_t)(32 + sr) * TDIM + (kt_) * 64 + sx, V2[bi] + (32 + sr) * 64 + sc * 8); }

#pragma unroll 1
  for (int seg = 0; seg < 2; ++seg) {
    const int qt = seg ? bx : (31 - bx);  // long tile first
    const int q0 = qt * 64;
    const int nkt = qt + 1;

    // Q fragments (B-operand of S^T: col=q=rin, k=d)
    bf16x8 aq[2];
    {
      const size_t qr = base3 + (size_t)(q0 + wv * 16 + rin) * 3072 + h * 64;
      aq[0] = *(const bf16x8*)(qkv + qr + quad * 8);
      aq[1] = *(const bf16x8*)(qkv + qr + 32 + quad * 8);
    }

    f32x4 o[4] = {};
    f32x4 ol = {};

    STAGE(0, 0)
    asm volatile("s_waitcnt vmcnt(0)" ::: "memory");  // tile0 landed
    S_BARRIER();

    for (int kt = 0; kt < nkt; ++kt) {
      const bf16_t* Kb = K2[kt & 1];
      const bf16_t* Vb = V2[kt & 1];
      // depth-1 prefetch into buf^1 (tile kt-1's reads all retired pre-barrier)
      if (kt + 1 < nkt) STAGE((kt + 1) & 1, kt + 1)
      // ---- S^T = K.Q^T : 8 MFMA (M=key, N=q)
      f32x4 st[4] = {};
#pragma unroll
      for (int ki = 0; ki < 2; ++ki) {
#pragma unroll
        for (int kf = 0; kf < 4; ++kf) {
          const bf16x8 ak = *(const bf16x8*)(Kb + (kf * 16 + rin) * 64 +
                                             (((ki * 4 + quad) ^ (rin & 7)) * 8));
          st[kf] = __builtin_amdgcn_mfma_f32_16x16x32_bf16(ak, aq[ki], st[kf], 0, 0, 0);
        }
      }
      // ---- softmax (no max-sub) + pack into PV A-frags (k = quad*4+r)
      const bool maskt = (kt == qt);
      const int qg = q0 + wv * 16 + rin;
      short4v pf[4];
#pragma unroll
      for (int kf = 0; kf < 4; ++kf)
#pragma unroll
        for (int r = 0; r < 4; ++r) {
          const int kg = kt * 64 + kf * 16 + quad * 4 + r;
          float p = __builtin_amdgcn_exp2f(st[kf][r] * 0.18033688f);
          if (maskt && kg > qg) p = 0.f;
          union { bf16_t bv; short sv; } cv;
          cv.bv = (bf16_t)p;
          pf[kf][r] = cv.sv;
        }
      // ---- PV + rowsum: 20 MFMA 16x16x16, B-frags b64 from V^T
#pragma unroll
      for (int kf = 0; kf < 4; ++kf) {
#pragma unroll
        for (int nd = 0; nd < 4; ++nd) {
          const short4v bv = *(const short4v*)(Vb + (nd * 16 + rin) * 64 +
                                               (((kf * 2 + (quad >> 1)) ^ (rin & 7)) * 8) +
                                               (quad & 1) * 4);
          o[nd] = __builtin_amdgcn_mfma_f32_16x16x16bf16_1k(pf[kf], bv, o[nd], 0, 0, 0);
        }
        ol = __builtin_amdgcn_mfma_f32_16x16x16bf16_1k(pf[kf], ones, ol, 0, 0, 0);
      }
      asm volatile("s_waitcnt vmcnt(0)" ::: "memory");  // next tile resident
      S_BARRIER();
    }

    // ---- epilogue: O C-frag col=d=rin, row=q=quad*4+r; l frag reg=q
#pragma unroll
    for (int r = 0; r < 4; ++r) {
      const float inv = 1.0f / ol[r];
      const size_t row = (size_t)b * TDIM + q0 + wv * 16 + quad * 4 + r;
#pragma unroll
      for (int nd = 0; nd < 4; ++nd)
        y[row * CDIM + h * 64 + nd * 16 + rin] = (bf16_t)(o[nd][r] * inv);
    }
  }
#undef STAGE
}

extern "C" void kernel_launch(void* const* d_in, const int* in_sizes, int n_in,
                              void* d_out, int out_size, void* d_ws, size_t ws_size,
                              hipStream_t stream) {
  const float* x      = (const float*)d_in[0];
  const float* w_attn = (const float*)d_in[1];
  const float* b_attn = (const float*)d_in[2];
  const float* w_proj = (const float*)d_in[3];
  const float* b_proj = (const float*)d_in[4];
  const float* ln1g   = (const float*)d_in[5];
  const float* ln1b   = (const float*)d_in[6];
  const float* ln2g   = (const float*)d_in[7];
  const float* ln2b   = (const float*)d_in[8];
  const float* w_fc   = (const float*)d_in[9];
  const float* b_fc   = (const float*)d_in[10];
  const float* w_fc2  = (const float*)d_in[11];
  const float* b_fc2  = (const float*)d_in[12];
  float* out = (float*)d_out;

  char* ws = (char*)d_ws;
  bf16_t* wTattn = (bf16_t*)(ws + 0);                    //  6291456 B (3072x1024)
  bf16_t* wTproj = (bf16_t*)(ws + 6291456);              //  2097152 B (1024x1024)
  bf16_t* wTfc   = (bf16_t*)(ws + 8388608);              //  8388608 B (4096x1024)
  bf16_t* wTfc2  = (bf16_t*)(ws + 16777216);             //  8388608 B (1024x4096)
  bf16_t* xn     = (bf16_t*)(ws + 25165824);             // 16777216 B (8192x1024); dead after qkv GEMM -> reused as vT
  float*  x2     = (float*)(ws + 41943040);              // 33554432 B (8192x1024)
  bf16_t* qkv    = (bf16_t*)(ws + 75497472);             // 50331648 B (8192x3072)
  bf16_t* yb     = (bf16_t*)(ws + 75497472 + 50331648);  // 16777216 B (8192x1024)
  bf16_t* hb     = (bf16_t*)(ws + 75497472);             // 67108864 B (8192x4096), reuses qkv+y
  bf16_t* vT     = xn;                                   // 16777216 B (4x16x64x2048), overlays xn

  // weights -> bf16 transposed
  transpose_cast<<<dim3(96, 32), 256, 0, stream>>>(w_attn, wTattn, 1024, 3072);
  transpose_cast<<<dim3(32, 32), 256, 0, stream>>>(w_proj, wTproj, 1024, 1024);
  transpose_cast<<<dim3(128, 32), 256, 0, stream>>>(w_fc, wTfc, 1024, 4096);
  transpose_cast<<<dim3(32, 128), 256, 0, stream>>>(w_fc2, wTfc2, 4096, 1024);

  // LN1 -> xn
  ln_kernel<<<8192, 256, 0, stream>>>(x, ln1g, ln1b, xn);
  // qkv = xn @ w_attn + b_attn   (bf16 out)
  gemm128<EPI_BF16><<<dim3(24, 32), 512, 0, stream>>>(xn, wTattn, b_attn, nullptr, qkv, 8192, 3072, 1024);
  // V -> V^T  (xn is dead now; vT overlays it)
  transpose_v<<<dim3(32, 16, 4), 256, 0, stream>>>(qkv, vT);
  // attention -> yb
  attn_kernel<<<dim3(1024), 256, 0, stream>>>(qkv, vT, yb);
  // x2 = x + yb @ w_proj + b_proj (fp32)
  gemm128<EPI_RESID><<<dim3(8, 32), 512, 0, stream>>>(yb, wTproj, b_proj, x, x2, 8192, 1024, 1024);
  // LN2 -> xn
  ln_kernel<<<8192, 256, 0, stream>>>(x2, ln2g, ln2b, xn);
  // hb = gelu(xn @ w_fc + b_fc)  (bf16)
  gemm256<EPI_GELU><<<dim3(16, 32), 512, 0, stream>>>(xn, wTfc, b_fc, nullptr, hb, 8192, 4096, 1024);
  // out = x2 + hb @ w_fc2 + b_fc2 (fp32)
  gemm128<EPI_RESID><<<dim3(8, 32), 512, 0, stream>>>(hb, wTfc2, b_fc2, x2, out, 8192, 1024, 4096);
}

// Round 7
// 482.863 us; speedup vs baseline: 1.0238x; 1.0238x over previous
//
#include <hip/hip_runtime.h>
#include <hip/hip_bf16.h>
#include <stdint.h>

typedef __bf16 bf16_t;
typedef __bf16 bf16x8 __attribute__((ext_vector_type(8)));
typedef __bf16 bf16x4 __attribute__((ext_vector_type(4)));
typedef float f32x4 __attribute__((ext_vector_type(4)));
typedef short short4v __attribute__((ext_vector_type(4)));

#define BDIM_B 4
#define TDIM 2048
#define CDIM 1024

// -------- async global->LDS (16B per lane, wave-uniform LDS base + lane*16) -----
__device__ __forceinline__ void gload16(const void* g, void* l) {
  using GP = const __attribute__((address_space(1))) char*;
  using LP = __attribute__((address_space(3))) char*;
  __builtin_amdgcn_global_load_lds((GP)(uintptr_t)g, (LP)(uint32_t)(uintptr_t)l, 16, 0, 0);
}

#define S_BARRIER() asm volatile("s_barrier" ::: "memory")

// ---------------- weight transpose + fp32->bf16 cast:  Wt[n][k] = W[k][n] -------
__global__ __launch_bounds__(256)
void transpose_cast(const float* __restrict__ W, bf16_t* __restrict__ Wt, int K, int N) {
  __shared__ float tile[32][33];
  const int tx = threadIdx.x & 31, ty = threadIdx.x >> 5;  // 32 x 8
  const int n0 = blockIdx.x * 32, k0 = blockIdx.y * 32;
#pragma unroll
  for (int j = 0; j < 32; j += 8)
    tile[ty + j][tx] = W[(size_t)(k0 + ty + j) * N + n0 + tx];
  __syncthreads();
#pragma unroll
  for (int j = 0; j < 32; j += 8)
    Wt[(size_t)(n0 + ty + j) * K + k0 + tx] = (bf16_t)tile[tx][ty + j];
}

// ---------------- V pre-transpose: vT[b][h][d][t] = qkv V-part ------------------
__global__ __launch_bounds__(256)
void transpose_v(const bf16_t* __restrict__ qkv, bf16_t* __restrict__ vT) {
  __shared__ bf16_t tile[64 * 64];
  const int tt = blockIdx.x;  // t0 = tt*64
  const int h = blockIdx.y, b = blockIdx.z;
  const int tid = threadIdx.x;
  const int sr = tid >> 3, sc = tid & 7;
  const bf16_t* src = qkv + (size_t)(b * TDIM) * 3072 + 2048 + h * 64;
#pragma unroll
  for (int p = 0; p < 2; ++p) {
    const int t = p * 32 + sr;
    *(uint4*)(tile + t * 64 + ((sc ^ (t & 7)) * 8)) =
        *(const uint4*)(src + (size_t)(tt * 64 + t) * 3072 + sc * 8);
  }
  __syncthreads();
  const int d = tid >> 2, tq = tid & 3;
  bf16_t* dst = vT + ((size_t)((b * 16 + h) * 64 + d)) * TDIM + tt * 64;
#pragma unroll
  for (int p = 0; p < 2; ++p) {
    union { uint4 u; bf16_t e[8]; } o;
#pragma unroll
    for (int j = 0; j < 8; ++j) {
      const int t = p * 32 + tq * 8 + j;
      o.e[j] = tile[t * 64 + (((d >> 3) ^ (t & 7)) * 8) + (d & 7)];
    }
    *(uint4*)(dst + p * 32 + tq * 8) = o.u;
  }
}

// ---------------- fused LayerNorm (fp32 in) -> bf16 out -------------------------
__global__ __launch_bounds__(256)
void ln_kernel(const float* __restrict__ x, const float* __restrict__ g,
               const float* __restrict__ bta, bf16_t* __restrict__ out) {
  const size_t row = blockIdx.x;
  const int tid = threadIdx.x;
  const float4 v = ((const float4*)(x + row * CDIM))[tid];
  float s = v.x + v.y + v.z + v.w;
#pragma unroll
  for (int off = 1; off < 64; off <<= 1) s += __shfl_xor(s, off);
  __shared__ float r1[4], r2[4];
  const int wv = tid >> 6, lane = tid & 63;
  if (!lane) r1[wv] = s;
  __syncthreads();
  const float mu = (r1[0] + r1[1] + r1[2] + r1[3]) * (1.f / CDIM);
  const float dx = v.x - mu, dy = v.y - mu, dz = v.z - mu, dw = v.w - mu;
  float q = dx * dx + dy * dy + dz * dz + dw * dw;
#pragma unroll
  for (int off = 1; off < 64; off <<= 1) q += __shfl_xor(q, off);
  if (!lane) r2[wv] = q;
  __syncthreads();
  const float var = (r2[0] + r2[1] + r2[2] + r2[3]) * (1.f / CDIM);
  const float rs = rsqrtf(var + 1e-5f);
  const float4 gg = ((const float4*)g)[tid];
  const float4 bb = ((const float4*)bta)[tid];
  bf16x4 o;
  o[0] = (bf16_t)(dx * rs * gg.x + bb.x);
  o[1] = (bf16_t)(dy * rs * gg.y + bb.y);
  o[2] = (bf16_t)(dz * rs * gg.z + bb.z);
  o[3] = (bf16_t)(dw * rs * gg.w + bb.w);
  ((bf16x4*)(out + row * CDIM))[tid] = o;
}

enum { EPI_BF16 = 0, EPI_RESID = 1, EPI_GELU = 2 };

// ---------------- 256x256 8-wave m201-faithful counted-vmcnt GEMM ---------------
// BM=BN=256, BK=64, 512 thr (8 waves 2x4, wave tile 128x64), 2-buf 128KiB.
// Staging unit = half-tile (128 rows x 64 k = 2 gload16/thread). Stagger:
// during tile t stage {t+1.B1 -> other buf (ph0); t+2.B0 (ph2); t+2.A0,A1 (ph3)
// -> CURRENT buf, each after its region's last-reader barrier}. Fence ONCE per
// tile: vmcnt(6) at ph3 end retires exactly tile t+1's 8 loads (aged ~2 tiles);
// never drains to 0 in the loop. WAR safety: every wave's ds_reads are consumed
// by its MFMAs (lgkmcnt) before it reaches the phase-closing barrier; staged
// data returns >=200cy after issue. Tails: clamped stray stages into
// never-read-again regions keep the fence count exact.
template <int EPI>
__global__ __launch_bounds__(512)
void gemm256(const bf16_t* __restrict__ A, const bf16_t* __restrict__ Bt,
             const float* __restrict__ bias, const float* __restrict__ resid,
             void* __restrict__ outv, int M, int N, int K) {
  __shared__ bf16_t sA[2][256 * 64];
  __shared__ bf16_t sB[2][256 * 64];
  const int tid = threadIdx.x;
  const int lane = tid & 63, wv = tid >> 6;
  const int wm = wv >> 2, wn = wv & 3;
  const int rin = lane & 15, quad = lane >> 4;

  const int nwg = gridDim.x * gridDim.y;
  const int bid = blockIdx.y * gridDim.x + blockIdx.x;
  const int swzb = (bid & 7) * (nwg >> 3) + (bid >> 3);
  const int bx = swzb % gridDim.x, by = swzb / gridDim.x;
  const int m0 = by * 256, n0 = bx * 256;

  // cooperative half-tile staging: row r0 (+64), chunk cc, pre-swizzled source
  const int r0 = tid >> 3, cc = tid & 7;
  const int sxo = (cc ^ (r0 & 7)) * 8;
  const bf16_t* gA = A + (size_t)(m0 + r0) * K + sxo;
  const bf16_t* gB = Bt + (size_t)(n0 + r0) * K + sxo;
  const int ldst = r0 * 64 + cc * 8;  // wave-uniform base + lane*16 (verified)

#define STGA(buf, h, kk) { \
    gload16(gA + (size_t)((h) * 128) * K + (kk), (buf) + (h) * 128 * 64 + ldst);              \
    gload16(gA + (size_t)((h) * 128 + 64) * K + (kk), (buf) + ((h) * 128 + 64) * 64 + ldst); }
#define STGB(buf, h, kk) { \
    gload16(gB + (size_t)((h) * 128) * K + (kk), (buf) + (h) * 128 * 64 + ldst);              \
    gload16(gB + (size_t)((h) * 128 + 64) * K + (kk), (buf) + ((h) * 128 + 64) * 64 + ldst); }

  const int ck0 = (quad ^ (rin & 7)) * 8;
  const int ck1 = ((4 + quad) ^ (rin & 7)) * 8;
  const int aBase = (wm * 128 + rin) * 64;
  const int bBase = (wn * 64 + rin) * 64;

  f32x4 acc[8][4] = {};
  bf16x8 af[8][2], bfr[4][2];

#define RDA(mi) { af[mi][0] = *(const bf16x8*)(rA + aBase + (mi)*1024 + ck0); \
                  af[mi][1] = *(const bf16x8*)(rA + aBase + (mi)*1024 + ck1); }
#define RDB(ni) { bfr[ni][0] = *(const bf16x8*)(rB + bBase + (ni)*1024 + ck0); \
                  bfr[ni][1] = *(const bf16x8*)(rB + bBase + (ni)*1024 + ck1); }
#define MM(mi, ni) { acc[mi][ni] = __builtin_amdgcn_mfma_f32_16x16x32_bf16(af[mi][0], bfr[ni][0], acc[mi][ni], 0, 0, 0); \
                     acc[mi][ni] = __builtin_amdgcn_mfma_f32_16x16x32_bf16(af[mi][1], bfr[ni][1], acc[mi][ni], 0, 0, 0); }

  const int NT = K >> 6;

  // prologue: tile0 all 4 halves, then tile1 {B0,A0,A1}; fence leaves the trio
  {
    const int k1 = (NT > 1 ? 1 : 0) * 64;
    STGA(sA[0], 0, 0); STGB(sB[0], 0, 0); STGA(sA[0], 1, 0); STGB(sB[0], 1, 0);
    STGB(sB[1], 0, k1); STGA(sA[1], 0, k1); STGA(sA[1], 1, k1);
  }
  asm volatile("s_waitcnt vmcnt(6)" ::: "memory");  // tile0 landed; t1 trio pending
  S_BARRIER();

  for (int t = 0; t < NT; ++t) {
    const bf16_t* rA = sA[t & 1];
    const bf16_t* rB = sB[t & 1];
    bf16_t* wA = sA[(t & 1) ^ 1];
    bf16_t* wB = sB[(t & 1) ^ 1];
    const int kk1 = (t + 1 < NT ? t + 1 : NT - 1) * 64;  // clamp -> dead buf
    const int kk2 = (t + 2 < NT ? t + 2 : NT - 1) * 64;  // clamp -> after-last-read

    // ph0: frags (mi0-3, ni0-1); stage t+1.B1 -> other buf
    RDA(0) RDA(1) RDA(2) RDA(3) RDB(0) RDB(1)
    STGB(wB, 1, kk1);
    S_BARRIER();
    __builtin_amdgcn_s_setprio(1);
    MM(0, 0) MM(0, 1) MM(1, 0) MM(1, 1) MM(2, 0) MM(2, 1) MM(3, 0) MM(3, 1)
    __builtin_amdgcn_s_setprio(0);
    S_BARRIER();

    // ph1: frags (ni2-3)
    RDB(2) RDB(3)
    S_BARRIER();
    __builtin_amdgcn_s_setprio(1);
    MM(0, 2) MM(0, 3) MM(1, 2) MM(1, 3) MM(2, 2) MM(2, 3) MM(3, 2) MM(3, 3)
    __builtin_amdgcn_s_setprio(0);
    S_BARRIER();

    // ph2: frags (mi4-7); stage t+2.B0 -> current buf (B last read ph1, barrier passed)
    RDA(4) RDA(5) RDA(6) RDA(7)
    STGB(sB[t & 1], 0, kk2);
    S_BARRIER();
    __builtin_amdgcn_s_setprio(1);
    MM(4, 0) MM(4, 1) MM(5, 0) MM(5, 1) MM(6, 0) MM(6, 1) MM(7, 0) MM(7, 1)
    __builtin_amdgcn_s_setprio(0);
    S_BARRIER();

    // ph3: stage t+2.A0,A1 -> current buf (A last read ph2, barrier passed);
    // single per-tile fence: retire exactly tile t+1's 8 loads, keep t+2 trio
    STGA(sA[t & 1], 0, kk2); STGA(sA[t & 1], 1, kk2);
    __builtin_amdgcn_s_setprio(1);
    MM(4, 2) MM(4, 3) MM(5, 2) MM(5, 3) MM(6, 2) MM(6, 3) MM(7, 2) MM(7, 3)
    __builtin_amdgcn_s_setprio(0);
    asm volatile("s_waitcnt vmcnt(6)" ::: "memory");
    S_BARRIER();
  }
  asm volatile("s_waitcnt vmcnt(0)" ::: "memory");  // drain stray clamped loads

  const int rbase = m0 + wm * 128 + quad * 4;
  const int cbase = n0 + wn * 64 + rin;
#pragma unroll
  for (int mi = 0; mi < 8; ++mi)
#pragma unroll
    for (int ni = 0; ni < 4; ++ni)
#pragma unroll
      for (int r = 0; r < 4; ++r) {
        const int m = rbase + mi * 16 + r;
        const int n = cbase + ni * 16;
        float v = acc[mi][ni][r] + bias[n];
        if (EPI == EPI_RESID) v += resid[(size_t)m * N + n];
        if (EPI == EPI_GELU) v = 0.5f * v * (1.0f + erff(v * 0.7071067811865476f));
        if (EPI == EPI_RESID)
          ((float*)outv)[(size_t)m * N + n] = v;
        else
          ((bf16_t*)outv)[(size_t)m * N + n] = (bf16_t)v;
      }
#undef STGA
#undef STGB
#undef RDA
#undef RDB
#undef MM
}

// ---------------- 256x128 8-wave ring-3 MFMA GEMM (for N=1024 / qkv grids) ------
template <int EPI>
__global__ __launch_bounds__(512)
void gemm128(const bf16_t* __restrict__ A, const bf16_t* __restrict__ Bt,
             const float* __restrict__ bias, const float* __restrict__ resid,
             void* __restrict__ outv, int M, int N, int K) {
  __shared__ bf16_t sA[3][256 * 64];
  __shared__ bf16_t sB[3][128 * 64];
  const int tid = threadIdx.x;
  const int lane = tid & 63, wv = tid >> 6;
  const int wm = wv >> 1, wn = wv & 1;
  const int rin = lane & 15, quad = lane >> 4;

  const int nwg = gridDim.x * gridDim.y;
  const int bid = blockIdx.y * gridDim.x + blockIdx.x;
  const int swzb = (bid & 7) * (nwg >> 3) + (bid >> 3);
  const int bx = swzb % gridDim.x, by = swzb / gridDim.x;
  const int m0 = by * 256, n0 = bx * 128;

  const int c8 = (lane & 7) ^ ((lane >> 3) & 7);
  const bf16_t* srcA = A + (size_t)(m0 + 8 * wv + (lane >> 3)) * K + c8 * 8;
  const int dstA = (8 * wv) * 64;
  const bf16_t* srcB = Bt + (size_t)(n0 + (wv >> 2) * 64 + (wv & 3) * 8 + (lane >> 3)) * K + c8 * 8;
  const int dstB = ((wv >> 2) * 64 + (wv & 3) * 8) * 64;

#define STA(buf, r, kk) gload16(srcA + (size_t)(64 * (r)) * K + (kk), (buf) + dstA + 64 * (r) * 64)
#define STB(buf, r, kk) gload16(srcB + (size_t)(32 * (r)) * K + (kk), (buf) + dstB + 32 * (r) * 64)

  const int ck0 = (quad ^ (rin & 7)) * 8;
  const int ck1 = ((4 + quad) ^ (rin & 7)) * 8;
  const int aBase = (wm * 64 + rin) * 64;
  const int bBase = (wn * 64 + rin) * 64;

  f32x4 acc[4][4] = {};
  bf16x8 af[4][2], bfr[4][2];

#define RDA(mi) { af[mi][0] = *(const bf16x8*)(rA + aBase + (mi)*1024 + ck0); \
                  af[mi][1] = *(const bf16x8*)(rA + aBase + (mi)*1024 + ck1); }
#define RDB(ni) { bfr[ni][0] = *(const bf16x8*)(rB + bBase + (ni)*1024 + ck0); \
                  bfr[ni][1] = *(const bf16x8*)(rB + bBase + (ni)*1024 + ck1); }
#define MM(mi, ni) { acc[mi][ni] = __builtin_amdgcn_mfma_f32_16x16x32_bf16(af[mi][0], bfr[ni][0], acc[mi][ni], 0, 0, 0); \
                     acc[mi][ni] = __builtin_amdgcn_mfma_f32_16x16x32_bf16(af[mi][1], bfr[ni][1], acc[mi][ni], 0, 0, 0); }

  const int NT = K >> 6;

  STA(sA[0], 0, 0); STA(sA[0], 1, 0); STA(sA[0], 2, 0); STA(sA[0], 3, 0); STB(sB[0], 0, 0);
  STB(sB[0], 1, 0);
  STA(sA[1], 0, 64); STA(sA[1], 1, 64); STA(sA[1], 2, 64); STA(sA[1], 3, 64); STB(sB[1], 0, 64);
  STB(sB[1], 1, 64);
  asm volatile("s_waitcnt vmcnt(7)" ::: "memory");
  S_BARRIER();

  int rb = 0, wb = 2;
  for (int t = 0; t < NT; ++t) {
    const bf16_t* rA = sA[rb];
    const bf16_t* rB = sB[rb];
    bf16_t* wA = sA[wb];
    bf16_t* wB = sB[wb];
    const int kk = (t + 2 < NT ? t + 2 : NT - 1) * 64;

    RDA(0) RDA(1) RDA(2) RDA(3) RDB(0) RDB(1)
    asm volatile("s_waitcnt vmcnt(6)" ::: "memory");
    S_BARRIER();
    STA(wA, 0, kk); STA(wA, 1, kk); STA(wA, 2, kk); STA(wA, 3, kk); STB(wB, 0, kk);
    __builtin_amdgcn_s_setprio(1);
    MM(0, 0) MM(0, 1) MM(1, 0) MM(1, 1) MM(2, 0) MM(2, 1) MM(3, 0) MM(3, 1)
    __builtin_amdgcn_s_setprio(0);

    RDB(2) RDB(3)
    asm volatile("s_waitcnt vmcnt(6)" ::: "memory");
    S_BARRIER();
    STB(wB, 1, kk);
    __builtin_amdgcn_s_setprio(1);
    MM(0, 2) MM(0, 3) MM(1, 2) MM(1, 3) MM(2, 2) MM(2, 3) MM(3, 2) MM(3, 3)
    __builtin_amdgcn_s_setprio(0);

    rb = (rb == 2) ? 0 : rb + 1;
    wb = (wb == 2) ? 0 : wb + 1;
  }
  asm volatile("s_waitcnt vmcnt(0)" ::: "memory");

  const int rbase = m0 + wm * 64 + quad * 4;
  const int cbase = n0 + wn * 64 + rin;
#pragma unroll
  for (int mi = 0; mi < 4; ++mi)
#pragma unroll
    for (int ni = 0; ni < 4; ++ni)
#pragma unroll
      for (int r = 0; r < 4; ++r) {
        const int m = rbase + mi * 16 + r;
        const int n = cbase + ni * 16;
        float v = acc[mi][ni][r] + bias[n];
        if (EPI == EPI_RESID) v += resid[(size_t)m * N + n];
        if (EPI == EPI_GELU) v = 0.5f * v * (1.0f + erff(v * 0.7071067811865476f));
        if (EPI == EPI_RESID)
          ((float*)outv)[(size_t)m * N + n] = v;
        else
          ((bf16_t*)outv)[(size_t)m * N + n] = (bf16_t)v;
      }
#undef STA
#undef STB
#undef RDA
#undef RDB
#undef MM
}

// ---------------- flash attention v4.1, causal, H=16 D=64 ----------------------
__global__ __launch_bounds__(256)
void attn_kernel(const bf16_t* __restrict__ qkv, const bf16_t* __restrict__ vT,
                 bf16_t* __restrict__ y) {
  const int id = blockIdx.x;
  const int bx = id >> 6;
  const int h = id & 15, b = (id >> 4) & 3;
  const int tid = threadIdx.x, lane = tid & 63, wv = tid >> 6;
  const int rin = lane & 15, quad = lane >> 4;

  __shared__ bf16_t K2[2][64 * 64];  // K [t][d], chunk ^ (t&7)
  __shared__ bf16_t V2[2][64 * 64];  // V^T [d][t], chunk ^ (d&7)

  const size_t base3 = (size_t)(b * TDIM) * 3072;
  const bf16_t* Kg = qkv + base3 + 1024 + h * 64;                 // + t*3072
  const bf16_t* Vg = vT + (size_t)((b * 16 + h) * 64) * TDIM;     // + d*2048
  const int sr = tid >> 3, sc = tid & 7;  // staging: row sr(+32), chunk sc
  const int sx = (sc ^ (sr & 7)) * 8;     // pre-swizzled source chunk
  const short4v ones = {(short)0x3F80, (short)0x3F80, (short)0x3F80, (short)0x3F80};

#define STAGE(bi, kt_) { \
    gload16(Kg + (size_t)((kt_) * 64 + sr) * 3072 + sx,      K2[bi] + sr * 64 + sc * 8);        \
    gload16(Kg + (size_t)((kt_) * 64 + 32 + sr) * 3072 + sx, K2[bi] + (32 + sr) * 64 + sc * 8); \
    gload16(Vg + (size_t)sr * TDIM + (kt_) * 64 + sx,        V2[bi] + sr * 64 + sc * 8);        \
    gload16(Vg + (size_t)(32 + sr) * TDIM + (kt_) * 64 + sx, V2[bi] + (32 + sr) * 64 + sc * 8); }

#pragma unroll 1
  for (int seg = 0; seg < 2; ++seg) {
    const int qt = seg ? bx : (31 - bx);  // long tile first
    const int q0 = qt * 64;
    const int nkt = qt + 1;

    // Q fragments (B-operand of S^T: col=q=rin, k=d)
    bf16x8 aq[2];
    {
      const size_t qr = base3 + (size_t)(q0 + wv * 16 + rin) * 3072 + h * 64;
      aq[0] = *(const bf16x8*)(qkv + qr + quad * 8);
      aq[1] = *(const bf16x8*)(qkv + qr + 32 + quad * 8);
    }

    f32x4 o[4] = {};
    f32x4 ol = {};

    STAGE(0, 0)
    asm volatile("s_waitcnt vmcnt(0)" ::: "memory");  // tile0 landed
    S_BARRIER();

    for (int kt = 0; kt < nkt; ++kt) {
      const bf16_t* Kb = K2[kt & 1];
      const bf16_t* Vb = V2[kt & 1];
      // depth-1 prefetch into buf^1 (tile kt-1's reads all retired pre-barrier)
      if (kt + 1 < nkt) STAGE((kt + 1) & 1, kt + 1)
      // ---- S^T = K.Q^T : 8 MFMA (M=key, N=q)
      f32x4 st[4] = {};
#pragma unroll
      for (int ki = 0; ki < 2; ++ki) {
#pragma unroll
        for (int kf = 0; kf < 4; ++kf) {
          const bf16x8 ak = *(const bf16x8*)(Kb + (kf * 16 + rin) * 64 +
                                             (((ki * 4 + quad) ^ (rin & 7)) * 8));
          st[kf] = __builtin_amdgcn_mfma_f32_16x16x32_bf16(ak, aq[ki], st[kf], 0, 0, 0);
        }
      }
      // ---- softmax (no max-sub) + pack into PV A-frags (k = quad*4+r)
      const bool maskt = (kt == qt);
      const int qg = q0 + wv * 16 + rin;
      short4v pf[4];
#pragma unroll
      for (int kf = 0; kf < 4; ++kf)
#pragma unroll
        for (int r = 0; r < 4; ++r) {
          const int kg = kt * 64 + kf * 16 + quad * 4 + r;
          float p = __builtin_amdgcn_exp2f(st[kf][r] * 0.18033688f);
          if (maskt && kg > qg) p = 0.f;
          union { bf16_t bv; short sv; } cv;
          cv.bv = (bf16_t)p;
          pf[kf][r] = cv.sv;
        }
      // ---- PV + rowsum: 20 MFMA 16x16x16, B-frags b64 from V^T
#pragma unroll
      for (int kf = 0; kf < 4; ++kf) {
#pragma unroll
        for (int nd = 0; nd < 4; ++nd) {
          const short4v bv = *(const short4v*)(Vb + (nd * 16 + rin) * 64 +
                                               (((kf * 2 + (quad >> 1)) ^ (rin & 7)) * 8) +
                                               (quad & 1) * 4);
          o[nd] = __builtin_amdgcn_mfma_f32_16x16x16bf16_1k(pf[kf], bv, o[nd], 0, 0, 0);
        }
        ol = __builtin_amdgcn_mfma_f32_16x16x16bf16_1k(pf[kf], ones, ol, 0, 0, 0);
      }
      asm volatile("s_waitcnt vmcnt(0)" ::: "memory");  // next tile resident
      S_BARRIER();
    }

    // ---- epilogue: O C-frag col=d=rin, row=q=quad*4+r; l frag reg=q
#pragma unroll
    for (int r = 0; r < 4; ++r) {
      const float inv = 1.0f / ol[r];
      const size_t row = (size_t)b * TDIM + q0 + wv * 16 + quad * 4 + r;
#pragma unroll
      for (int nd = 0; nd < 4; ++nd)
        y[row * CDIM + h * 64 + nd * 16 + rin] = (bf16_t)(o[nd][r] * inv);
    }
  }
#undef STAGE
}

extern "C" void kernel_launch(void* const* d_in, const int* in_sizes, int n_in,
                              void* d_out, int out_size, void* d_ws, size_t ws_size,
                              hipStream_t stream) {
  const float* x      = (const float*)d_in[0];
  const float* w_attn = (const float*)d_in[1];
  const float* b_attn = (const float*)d_in[2];
  const float* w_proj = (const float*)d_in[3];
  const float* b_proj = (const float*)d_in[4];
  const float* ln1g   = (const float*)d_in[5];
  const float* ln1b   = (const float*)d_in[6];
  const float* ln2g   = (const float*)d_in[7];
  const float* ln2b   = (const float*)d_in[8];
  const float* w_fc   = (const float*)d_in[9];
  const float* b_fc   = (const float*)d_in[10];
  const float* w_fc2  = (const float*)d_in[11];
  const float* b_fc2  = (const float*)d_in[12];
  float* out = (float*)d_out;

  char* ws = (char*)d_ws;
  bf16_t* wTattn = (bf16_t*)(ws + 0);                    //  6291456 B (3072x1024)
  bf16_t* wTproj = (bf16_t*)(ws + 6291456);              //  2097152 B (1024x1024)
  bf16_t* wTfc   = (bf16_t*)(ws + 8388608);              //  8388608 B (4096x1024)
  bf16_t* wTfc2  = (bf16_t*)(ws + 16777216);             //  8388608 B (1024x4096)
  bf16_t* xn     = (bf16_t*)(ws + 25165824);             // 16777216 B (8192x1024); dead after qkv GEMM -> reused as vT
  float*  x2     = (float*)(ws + 41943040);              // 33554432 B (8192x1024)
  bf16_t* qkv    = (bf16_t*)(ws + 75497472);             // 50331648 B (8192x3072)
  bf16_t* yb     = (bf16_t*)(ws + 75497472 + 50331648);  // 16777216 B (8192x1024)
  bf16_t* hb     = (bf16_t*)(ws + 75497472);             // 67108864 B (8192x4096), reuses qkv+y
  bf16_t* vT     = xn;                                   // 16777216 B (4x16x64x2048), overlays xn

  // weights -> bf16 transposed
  transpose_cast<<<dim3(96, 32), 256, 0, stream>>>(w_attn, wTattn, 1024, 3072);
  transpose_cast<<<dim3(32, 32), 256, 0, stream>>>(w_proj, wTproj, 1024, 1024);
  transpose_cast<<<dim3(128, 32), 256, 0, stream>>>(w_fc, wTfc, 1024, 4096);
  transpose_cast<<<dim3(32, 128), 256, 0, stream>>>(w_fc2, wTfc2, 4096, 1024);

  // LN1 -> xn
  ln_kernel<<<8192, 256, 0, stream>>>(x, ln1g, ln1b, xn);
  // qkv = xn @ w_attn + b_attn   (bf16 out)
  gemm128<EPI_BF16><<<dim3(24, 32), 512, 0, stream>>>(xn, wTattn, b_attn, nullptr, qkv, 8192, 3072, 1024);
  // V -> V^T  (xn is dead now; vT overlays it)
  transpose_v<<<dim3(32, 16, 4), 256, 0, stream>>>(qkv, vT);
  // attention -> yb
  attn_kernel<<<dim3(1024), 256, 0, stream>>>(qkv, vT, yb);
  // x2 = x + yb @ w_proj + b_proj (fp32)
  gemm128<EPI_RESID><<<dim3(8, 32), 512, 0, stream>>>(yb, wTproj, b_proj, x, x2, 8192, 1024, 1024);
  // LN2 -> xn
  ln_kernel<<<8192, 256, 0, stream>>>(x2, ln2g, ln2b, xn);
  // hb = gelu(xn @ w_fc + b_fc)  (bf16)
  gemm256<EPI_GELU><<<dim3(16, 32), 512, 0, stream>>>(xn, wTfc, b_fc, nullptr, hb, 8192, 4096, 1024);
  // out = x2 + hb @ w_fc2 + b_fc2 (fp32)
  gemm128<EPI_RESID><<<dim3(8, 32), 512, 0, stream>>>(hb, wTfc2, b_fc2, x2, out, 8192, 1024, 4096);
}

// Round 8
// 480.631 us; speedup vs baseline: 1.0285x; 1.0046x over previous
//
#include <hip/hip_runtime.h>
#include <hip/hip_bf16.h>
#include <stdint.h>

typedef __bf16 bf16_t;
typedef __bf16 bf16x8 __attribute__((ext_vector_type(8)));
typedef __bf16 bf16x4 __attribute__((ext_vector_type(4)));
typedef float f32x4 __attribute__((ext_vector_type(4)));
typedef short short4v __attribute__((ext_vector_type(4)));

#define BDIM_B 4
#define TDIM 2048
#define CDIM 1024

// -------- async global->LDS (16B per lane, wave-uniform LDS base + lane*16) -----
__device__ __forceinline__ void gload16(const void* g, void* l) {
  using GP = const __attribute__((address_space(1))) char*;
  using LP = __attribute__((address_space(3))) char*;
  __builtin_amdgcn_global_load_lds((GP)(uintptr_t)g, (LP)(uint32_t)(uintptr_t)l, 16, 0, 0);
}

#define S_BARRIER() asm volatile("s_barrier" ::: "memory")

// ---------------- weight transpose + fp32->bf16 cast:  Wt[n][k] = W[k][n] -------
__global__ __launch_bounds__(256)
void transpose_cast(const float* __restrict__ W, bf16_t* __restrict__ Wt, int K, int N) {
  __shared__ float tile[32][33];
  const int tx = threadIdx.x & 31, ty = threadIdx.x >> 5;  // 32 x 8
  const int n0 = blockIdx.x * 32, k0 = blockIdx.y * 32;
#pragma unroll
  for (int j = 0; j < 32; j += 8)
    tile[ty + j][tx] = W[(size_t)(k0 + ty + j) * N + n0 + tx];
  __syncthreads();
#pragma unroll
  for (int j = 0; j < 32; j += 8)
    Wt[(size_t)(n0 + ty + j) * K + k0 + tx] = (bf16_t)tile[tx][ty + j];
}

// ---------------- V pre-transpose: vT[b][h][d][t] = qkv V-part ------------------
__global__ __launch_bounds__(256)
void transpose_v(const bf16_t* __restrict__ qkv, bf16_t* __restrict__ vT) {
  __shared__ bf16_t tile[64 * 64];
  const int tt = blockIdx.x;  // t0 = tt*64
  const int h = blockIdx.y, b = blockIdx.z;
  const int tid = threadIdx.x;
  const int sr = tid >> 3, sc = tid & 7;
  const bf16_t* src = qkv + (size_t)(b * TDIM) * 3072 + 2048 + h * 64;
#pragma unroll
  for (int p = 0; p < 2; ++p) {
    const int t = p * 32 + sr;
    *(uint4*)(tile + t * 64 + ((sc ^ (t & 7)) * 8)) =
        *(const uint4*)(src + (size_t)(tt * 64 + t) * 3072 + sc * 8);
  }
  __syncthreads();
  const int d = tid >> 2, tq = tid & 3;
  bf16_t* dst = vT + ((size_t)((b * 16 + h) * 64 + d)) * TDIM + tt * 64;
#pragma unroll
  for (int p = 0; p < 2; ++p) {
    union { uint4 u; bf16_t e[8]; } o;
#pragma unroll
    for (int j = 0; j < 8; ++j) {
      const int t = p * 32 + tq * 8 + j;
      o.e[j] = tile[t * 64 + (((d >> 3) ^ (t & 7)) * 8) + (d & 7)];
    }
    *(uint4*)(dst + p * 32 + tq * 8) = o.u;
  }
}

// ---------------- fused LayerNorm (fp32 in) -> bf16 out -------------------------
__global__ __launch_bounds__(256)
void ln_kernel(const float* __restrict__ x, const float* __restrict__ g,
               const float* __restrict__ bta, bf16_t* __restrict__ out) {
  const size_t row = blockIdx.x;
  const int tid = threadIdx.x;
  const float4 v = ((const float4*)(x + row * CDIM))[tid];
  float s = v.x + v.y + v.z + v.w;
#pragma unroll
  for (int off = 1; off < 64; off <<= 1) s += __shfl_xor(s, off);
  __shared__ float r1[4], r2[4];
  const int wv = tid >> 6, lane = tid & 63;
  if (!lane) r1[wv] = s;
  __syncthreads();
  const float mu = (r1[0] + r1[1] + r1[2] + r1[3]) * (1.f / CDIM);
  const float dx = v.x - mu, dy = v.y - mu, dz = v.z - mu, dw = v.w - mu;
  float q = dx * dx + dy * dy + dz * dz + dw * dw;
#pragma unroll
  for (int off = 1; off < 64; off <<= 1) q += __shfl_xor(q, off);
  if (!lane) r2[wv] = q;
  __syncthreads();
  const float var = (r2[0] + r2[1] + r2[2] + r2[3]) * (1.f / CDIM);
  const float rs = rsqrtf(var + 1e-5f);
  const float4 gg = ((const float4*)g)[tid];
  const float4 bb = ((const float4*)bta)[tid];
  bf16x4 o;
  o[0] = (bf16_t)(dx * rs * gg.x + bb.x);
  o[1] = (bf16_t)(dy * rs * gg.y + bb.y);
  o[2] = (bf16_t)(dz * rs * gg.z + bb.z);
  o[3] = (bf16_t)(dw * rs * gg.w + bb.w);
  ((bf16x4*)(out + row * CDIM))[tid] = o;
}

enum { EPI_BF16 = 0, EPI_RESID = 1, EPI_GELU = 2 };

// ---------------- 256x256 8-wave barrier-free-within-tile GEMM ------------------
// BM=BN=256, BK=64, 512 thr (8 waves 2x4, wave tile 128x64), 2-buf 128KiB.
// r7 lesson (arithmetic): per tile per CU, MFMA=2480cy and LDS-read=~1800-2300cy.
// Phase brackets [reads -> barrier -> MFMA -> barrier] put all 8 waves in the
// same phase -> LDS and MFMA pipes SERIALIZE (~7950cy/tile measured, MfmaUtil
// 25%). Fix: NO intra-tile barriers. Per tile: issue stage of t+1 (8 gload_lds,
// into the other buffer -- its readers all passed the previous tile-boundary
// barrier), issue all 24 ds_read_b128, run all 64 MFMA; compiler's fine-grained
// lgkmcnt streams reads into the MFMA pipe (LDS overlaps MFMA). ONE
// vmcnt(0)+barrier per tile boundary; loads aged a full tile (~2600cy >> 900cy
// HBM latency) so the drain is cheap.
template <int EPI>
__global__ __launch_bounds__(512)
void gemm256(const bf16_t* __restrict__ A, const bf16_t* __restrict__ Bt,
             const float* __restrict__ bias, const float* __restrict__ resid,
             void* __restrict__ outv, int M, int N, int K) {
  __shared__ bf16_t sA[2][256 * 64];
  __shared__ bf16_t sB[2][256 * 64];
  const int tid = threadIdx.x;
  const int lane = tid & 63, wv = tid >> 6;
  const int wm = wv >> 2, wn = wv & 3;
  const int rin = lane & 15, quad = lane >> 4;

  const int nwg = gridDim.x * gridDim.y;
  const int bid = blockIdx.y * gridDim.x + blockIdx.x;
  const int swzb = (bid & 7) * (nwg >> 3) + (bid >> 3);
  const int bx = swzb % gridDim.x, by = swzb / gridDim.x;
  const int m0 = by * 256, n0 = bx * 256;

  // cooperative staging: row r0 (+64 per second load), chunk cc, pre-swizzled src
  const int r0 = tid >> 3, cc = tid & 7;
  const int sxo = (cc ^ (r0 & 7)) * 8;
  const bf16_t* gA = A + (size_t)(m0 + r0) * K + sxo;
  const bf16_t* gB = Bt + (size_t)(n0 + r0) * K + sxo;
  const int ldst = r0 * 64 + cc * 8;  // == wave-uniform base + lane*16

#define STGA(buf, h, kk) { \
    gload16(gA + (size_t)((h) * 128) * K + (kk), (buf) + (h) * 128 * 64 + ldst);              \
    gload16(gA + (size_t)((h) * 128 + 64) * K + (kk), (buf) + ((h) * 128 + 64) * 64 + ldst); }
#define STGB(buf, h, kk) { \
    gload16(gB + (size_t)((h) * 128) * K + (kk), (buf) + (h) * 128 * 64 + ldst);              \
    gload16(gB + (size_t)((h) * 128 + 64) * K + (kk), (buf) + ((h) * 128 + 64) * 64 + ldst); }

  const int ck0 = (quad ^ (rin & 7)) * 8;
  const int ck1 = ((4 + quad) ^ (rin & 7)) * 8;
  const int aBase = (wm * 128 + rin) * 64;
  const int bBase = (wn * 64 + rin) * 64;

  f32x4 acc[8][4] = {};
  bf16x8 af[8][2], bfr[4][2];

#define RDA(mi) { af[mi][0] = *(const bf16x8*)(rA + aBase + (mi)*1024 + ck0); \
                  af[mi][1] = *(const bf16x8*)(rA + aBase + (mi)*1024 + ck1); }
#define RDB(ni) { bfr[ni][0] = *(const bf16x8*)(rB + bBase + (ni)*1024 + ck0); \
                  bfr[ni][1] = *(const bf16x8*)(rB + bBase + (ni)*1024 + ck1); }
#define MM(mi, ni) { acc[mi][ni] = __builtin_amdgcn_mfma_f32_16x16x32_bf16(af[mi][0], bfr[ni][0], acc[mi][ni], 0, 0, 0); \
                     acc[mi][ni] = __builtin_amdgcn_mfma_f32_16x16x32_bf16(af[mi][1], bfr[ni][1], acc[mi][ni], 0, 0, 0); }

  const int NT = K >> 6;

  // prologue: stage tile 0, drain, barrier
  STGA(sA[0], 0, 0); STGA(sA[0], 1, 0); STGB(sB[0], 0, 0); STGB(sB[0], 1, 0);
  asm volatile("s_waitcnt vmcnt(0)" ::: "memory");
  S_BARRIER();

  for (int t = 0; t < NT; ++t) {
    const bf16_t* rA = sA[t & 1];
    const bf16_t* rB = sB[t & 1];
    bf16_t* wA = sA[(t & 1) ^ 1];
    bf16_t* wB = sB[(t & 1) ^ 1];
    const int kk = (t + 1 < NT ? t + 1 : t) * 64;  // tail clamp -> dead buffer

    // stage all of tile t+1 (other buffer; its readers retired at last barrier)
    STGA(wA, 0, kk); STGA(wA, 1, kk); STGB(wB, 0, kk); STGB(wB, 1, kk);

    // all fragment reads + all MFMAs in one region: compiler-interleaved,
    // LDS read stream overlaps the MFMA pipe (no intra-tile barriers)
    RDA(0) RDA(1) RDA(2) RDA(3) RDB(0) RDB(1) RDB(2) RDB(3)
    RDA(4) RDA(5) RDA(6) RDA(7)
    __builtin_amdgcn_s_setprio(1);
    MM(0, 0) MM(0, 1) MM(1, 0) MM(1, 1) MM(2, 0) MM(2, 1) MM(3, 0) MM(3, 1)
    MM(0, 2) MM(0, 3) MM(1, 2) MM(1, 3) MM(2, 2) MM(2, 3) MM(3, 2) MM(3, 3)
    MM(4, 0) MM(4, 1) MM(5, 0) MM(5, 1) MM(6, 0) MM(6, 1) MM(7, 0) MM(7, 1)
    MM(4, 2) MM(4, 3) MM(5, 2) MM(5, 3) MM(6, 2) MM(6, 3) MM(7, 2) MM(7, 3)
    __builtin_amdgcn_s_setprio(0);

    asm volatile("s_waitcnt vmcnt(0)" ::: "memory");  // tile t+1 resident
    S_BARRIER();
  }

  const int rbase = m0 + wm * 128 + quad * 4;
  const int cbase = n0 + wn * 64 + rin;
#pragma unroll
  for (int mi = 0; mi < 8; ++mi)
#pragma unroll
    for (int ni = 0; ni < 4; ++ni)
#pragma unroll
      for (int r = 0; r < 4; ++r) {
        const int m = rbase + mi * 16 + r;
        const int n = cbase + ni * 16;
        float v = acc[mi][ni][r] + bias[n];
        if (EPI == EPI_RESID) v += resid[(size_t)m * N + n];
        if (EPI == EPI_GELU) v = 0.5f * v * (1.0f + erff(v * 0.7071067811865476f));
        if (EPI == EPI_RESID)
          ((float*)outv)[(size_t)m * N + n] = v;
        else
          ((bf16_t*)outv)[(size_t)m * N + n] = (bf16_t)v;
      }
#undef STGA
#undef STGB
#undef RDA
#undef RDB
#undef MM
}

// ---------------- 256x128 8-wave ring-3 barrier-free-within-tile GEMM -----------
// Same discipline: per tile stage all 6 loads of t+2 (ring-3: that buffer's
// readers retired at end-of-(t-1) barrier), all 16 ds_reads, all 32 MFMA, then
// ONE vmcnt(6)+barrier (retires exactly tile t+1's 6 loads, aged >=1 tile).
template <int EPI>
__global__ __launch_bounds__(512)
void gemm128(const bf16_t* __restrict__ A, const bf16_t* __restrict__ Bt,
             const float* __restrict__ bias, const float* __restrict__ resid,
             void* __restrict__ outv, int M, int N, int K) {
  __shared__ bf16_t sA[3][256 * 64];
  __shared__ bf16_t sB[3][128 * 64];
  const int tid = threadIdx.x;
  const int lane = tid & 63, wv = tid >> 6;
  const int wm = wv >> 1, wn = wv & 1;
  const int rin = lane & 15, quad = lane >> 4;

  const int nwg = gridDim.x * gridDim.y;
  const int bid = blockIdx.y * gridDim.x + blockIdx.x;
  const int swzb = (bid & 7) * (nwg >> 3) + (bid >> 3);
  const int bx = swzb % gridDim.x, by = swzb / gridDim.x;
  const int m0 = by * 256, n0 = bx * 128;

  const int c8 = (lane & 7) ^ ((lane >> 3) & 7);
  const bf16_t* srcA = A + (size_t)(m0 + 8 * wv + (lane >> 3)) * K + c8 * 8;
  const int dstA = (8 * wv) * 64;
  const bf16_t* srcB = Bt + (size_t)(n0 + (wv >> 2) * 64 + (wv & 3) * 8 + (lane >> 3)) * K + c8 * 8;
  const int dstB = ((wv >> 2) * 64 + (wv & 3) * 8) * 64;

#define STA(buf, r, kk) gload16(srcA + (size_t)(64 * (r)) * K + (kk), (buf) + dstA + 64 * (r) * 64)
#define STB(buf, r, kk) gload16(srcB + (size_t)(32 * (r)) * K + (kk), (buf) + dstB + 32 * (r) * 64)

  const int ck0 = (quad ^ (rin & 7)) * 8;
  const int ck1 = ((4 + quad) ^ (rin & 7)) * 8;
  const int aBase = (wm * 64 + rin) * 64;
  const int bBase = (wn * 64 + rin) * 64;

  f32x4 acc[4][4] = {};
  bf16x8 af[4][2], bfr[4][2];

#define RDA(mi) { af[mi][0] = *(const bf16x8*)(rA + aBase + (mi)*1024 + ck0); \
                  af[mi][1] = *(const bf16x8*)(rA + aBase + (mi)*1024 + ck1); }
#define RDB(ni) { bfr[ni][0] = *(const bf16x8*)(rB + bBase + (ni)*1024 + ck0); \
                  bfr[ni][1] = *(const bf16x8*)(rB + bBase + (ni)*1024 + ck1); }
#define MM(mi, ni) { acc[mi][ni] = __builtin_amdgcn_mfma_f32_16x16x32_bf16(af[mi][0], bfr[ni][0], acc[mi][ni], 0, 0, 0); \
                     acc[mi][ni] = __builtin_amdgcn_mfma_f32_16x16x32_bf16(af[mi][1], bfr[ni][1], acc[mi][ni], 0, 0, 0); }

  const int NT = K >> 6;

  // prologue: stage tiles 0,1; fence keeps tile1 in flight
  STA(sA[0], 0, 0); STA(sA[0], 1, 0); STA(sA[0], 2, 0); STA(sA[0], 3, 0);
  STB(sB[0], 0, 0); STB(sB[0], 1, 0);
  STA(sA[1], 0, 64); STA(sA[1], 1, 64); STA(sA[1], 2, 64); STA(sA[1], 3, 64);
  STB(sB[1], 0, 64); STB(sB[1], 1, 64);
  asm volatile("s_waitcnt vmcnt(6)" ::: "memory");  // tile0 fully resident
  S_BARRIER();

  int rb = 0, wb = 2;
  for (int t = 0; t < NT; ++t) {
    const bf16_t* rA = sA[rb];
    const bf16_t* rB = sB[rb];
    bf16_t* wA = sA[wb];
    bf16_t* wB = sB[wb];
    const int kk = (t + 2 < NT ? t + 2 : NT - 1) * 64;  // tail clamp

    // stage all of tile t+2 (ring slot's readers retired at end-of-(t-1) barrier)
    STA(wA, 0, kk); STA(wA, 1, kk); STA(wA, 2, kk); STA(wA, 3, kk);
    STB(wB, 0, kk); STB(wB, 1, kk);

    // all reads + all MFMAs, no intra-tile barriers
    RDA(0) RDA(1) RDA(2) RDA(3) RDB(0) RDB(1) RDB(2) RDB(3)
    __builtin_amdgcn_s_setprio(1);
    MM(0, 0) MM(0, 1) MM(1, 0) MM(1, 1) MM(2, 0) MM(2, 1) MM(3, 0) MM(3, 1)
    MM(0, 2) MM(0, 3) MM(1, 2) MM(1, 3) MM(2, 2) MM(2, 3) MM(3, 2) MM(3, 3)
    __builtin_amdgcn_s_setprio(0);

    asm volatile("s_waitcnt vmcnt(6)" ::: "memory");  // tile t+1 resident (aged 1 tile)
    S_BARRIER();

    rb = (rb == 2) ? 0 : rb + 1;
    wb = (wb == 2) ? 0 : wb + 1;
  }
  asm volatile("s_waitcnt vmcnt(0)" ::: "memory");  // drain stray clamped loads

  const int rbase = m0 + wm * 64 + quad * 4;
  const int cbase = n0 + wn * 64 + rin;
#pragma unroll
  for (int mi = 0; mi < 4; ++mi)
#pragma unroll
    for (int ni = 0; ni < 4; ++ni)
#pragma unroll
      for (int r = 0; r < 4; ++r) {
        const int m = rbase + mi * 16 + r;
        const int n = cbase + ni * 16;
        float v = acc[mi][ni][r] + bias[n];
        if (EPI == EPI_RESID) v += resid[(size_t)m * N + n];
        if (EPI == EPI_GELU) v = 0.5f * v * (1.0f + erff(v * 0.7071067811865476f));
        if (EPI == EPI_RESID)
          ((float*)outv)[(size_t)m * N + n] = v;
        else
          ((bf16_t*)outv)[(size_t)m * N + n] = (bf16_t)v;
      }
#undef STA
#undef STB
#undef RDA
#undef RDB
#undef MM
}

// ---------------- flash attention v4.1, causal, H=16 D=64 ----------------------
__global__ __launch_bounds__(256)
void attn_kernel(const bf16_t* __restrict__ qkv, const bf16_t* __restrict__ vT,
                 bf16_t* __restrict__ y) {
  const int id = blockIdx.x;
  const int bx = id >> 6;
  const int h = id & 15, b = (id >> 4) & 3;
  const int tid = threadIdx.x, lane = tid & 63, wv = tid >> 6;
  const int rin = lane & 15, quad = lane >> 4;

  __shared__ bf16_t K2[2][64 * 64];  // K [t][d], chunk ^ (t&7)
  __shared__ bf16_t V2[2][64 * 64];  // V^T [d][t], chunk ^ (d&7)

  const size_t base3 = (size_t)(b * TDIM) * 3072;
  const bf16_t* Kg = qkv + base3 + 1024 + h * 64;                 // + t*3072
  const bf16_t* Vg = vT + (size_t)((b * 16 + h) * 64) * TDIM;     // + d*2048
  const int sr = tid >> 3, sc = tid & 7;  // staging: row sr(+32), chunk sc
  const int sx = (sc ^ (sr & 7)) * 8;     // pre-swizzled source chunk
  const short4v ones = {(short)0x3F80, (short)0x3F80, (short)0x3F80, (short)0x3F80};

#define STAGE(bi, kt_) { \
    gload16(Kg + (size_t)((kt_) * 64 + sr) * 3072 + sx,      K2[bi] + sr * 64 + sc * 8);        \
    gload16(Kg + (size_t)((kt_) * 64 + 32 + sr) * 3072 + sx, K2[bi] + (32 + sr) * 64 + sc * 8); \
    gload16(Vg + (size_t)sr * TDIM + (kt_) * 64 + sx,        V2[bi] + sr * 64 + sc * 8);        \
    gload16(Vg + (size_t)(32 + sr) * TDIM + (kt_) * 64 + sx, V2[bi] + (32 + sr) * 64 + sc * 8); }

#pragma unroll 1
  for (int seg = 0; seg < 2; ++seg) {
    const int qt = seg ? bx : (31 - bx);  // long tile first
    const int q0 = qt * 64;
    const int nkt = qt + 1;

    // Q fragments (B-operand of S^T: col=q=rin, k=d)
    bf16x8 aq[2];
    {
      const size_t qr = base3 + (size_t)(q0 + wv * 16 + rin) * 3072 + h * 64;
      aq[0] = *(const bf16x8*)(qkv + qr + quad * 8);
      aq[1] = *(const bf16x8*)(qkv + qr + 32 + quad * 8);
    }

    f32x4 o[4] = {};
    f32x4 ol = {};

    STAGE(0, 0)
    asm volatile("s_waitcnt vmcnt(0)" ::: "memory");  // tile0 landed
    S_BARRIER();

    for (int kt = 0; kt < nkt; ++kt) {
      const bf16_t* Kb = K2[kt & 1];
      const bf16_t* Vb = V2[kt & 1];
      // depth-1 prefetch into buf^1 (tile kt-1's reads all retired pre-barrier)
      if (kt + 1 < nkt) STAGE((kt + 1) & 1, kt + 1)
      // ---- S^T = K.Q^T : 8 MFMA (M=key, N=q)
      f32x4 st[4] = {};
#pragma unroll
      for (int ki = 0; ki < 2; ++ki) {
#pragma unroll
        for (int kf = 0; kf < 4; ++kf) {
          const bf16x8 ak = *(const bf16x8*)(Kb + (kf * 16 + rin) * 64 +
                                             (((ki * 4 + quad) ^ (rin & 7)) * 8));
          st[kf] = __builtin_amdgcn_mfma_f32_16x16x32_bf16(ak, aq[ki], st[kf], 0, 0, 0);
        }
      }
      // ---- softmax (no max-sub) + pack into PV A-frags (k = quad*4+r)
      const bool maskt = (kt == qt);
      const int qg = q0 + wv * 16 + rin;
      short4v pf[4];
#pragma unroll
      for (int kf = 0; kf < 4; ++kf)
#pragma unroll
        for (int r = 0; r < 4; ++r) {
          const int kg = kt * 64 + kf * 16 + quad * 4 + r;
          float p = __builtin_amdgcn_exp2f(st[kf][r] * 0.18033688f);
          if (maskt && kg > qg) p = 0.f;
          union { bf16_t bv; short sv; } cv;
          cv.bv = (bf16_t)p;
          pf[kf][r] = cv.sv;
        }
      // ---- PV + rowsum: 20 MFMA 16x16x16, B-frags b64 from V^T
#pragma unroll
      for (int kf = 0; kf < 4; ++kf) {
#pragma unroll
        for (int nd = 0; nd < 4; ++nd) {
          const short4v bv = *(const short4v*)(Vb + (nd * 16 + rin) * 64 +
                                               (((kf * 2 + (quad >> 1)) ^ (rin & 7)) * 8) +
                                               (quad & 1) * 4);
          o[nd] = __builtin_amdgcn_mfma_f32_16x16x16bf16_1k(pf[kf], bv, o[nd], 0, 0, 0);
        }
        ol = __builtin_amdgcn_mfma_f32_16x16x16bf16_1k(pf[kf], ones, ol, 0, 0, 0);
      }
      asm volatile("s_waitcnt vmcnt(0)" ::: "memory");  // next tile resident
      S_BARRIER();
    }

    // ---- epilogue: O C-frag col=d=rin, row=q=quad*4+r; l frag reg=q
#pragma unroll
    for (int r = 0; r < 4; ++r) {
      const float inv = 1.0f / ol[r];
      const size_t row = (size_t)b * TDIM + q0 + wv * 16 + quad * 4 + r;
#pragma unroll
      for (int nd = 0; nd < 4; ++nd)
        y[row * CDIM + h * 64 + nd * 16 + rin] = (bf16_t)(o[nd][r] * inv);
    }
  }
#undef STAGE
}

extern "C" void kernel_launch(void* const* d_in, const int* in_sizes, int n_in,
                              void* d_out, int out_size, void* d_ws, size_t ws_size,
                              hipStream_t stream) {
  const float* x      = (const float*)d_in[0];
  const float* w_attn = (const float*)d_in[1];
  const float* b_attn = (const float*)d_in[2];
  const float* w_proj = (const float*)d_in[3];
  const float* b_proj = (const float*)d_in[4];
  const float* ln1g   = (const float*)d_in[5];
  const float* ln1b   = (const float*)d_in[6];
  const float* ln2g   = (const float*)d_in[7];
  const float* ln2b   = (const float*)d_in[8];
  const float* w_fc   = (const float*)d_in[9];
  const float* b_fc   = (const float*)d_in[10];
  const float* w_fc2  = (const float*)d_in[11];
  const float* b_fc2  = (const float*)d_in[12];
  float* out = (float*)d_out;

  char* ws = (char*)d_ws;
  bf16_t* wTattn = (bf16_t*)(ws + 0);                    //  6291456 B (3072x1024)
  bf16_t* wTproj = (bf16_t*)(ws + 6291456);              //  2097152 B (1024x1024)
  bf16_t* wTfc   = (bf16_t*)(ws + 8388608);              //  8388608 B (4096x1024)
  bf16_t* wTfc2  = (bf16_t*)(ws + 16777216);             //  8388608 B (1024x4096)
  bf16_t* xn     = (bf16_t*)(ws + 25165824);             // 16777216 B (8192x1024); dead after qkv GEMM -> reused as vT
  float*  x2     = (float*)(ws + 41943040);              // 33554432 B (8192x1024)
  bf16_t* qkv    = (bf16_t*)(ws + 75497472);             // 50331648 B (8192x3072)
  bf16_t* yb     = (bf16_t*)(ws + 75497472 + 50331648);  // 16777216 B (8192x1024)
  bf16_t* hb     = (bf16_t*)(ws + 75497472);             // 67108864 B (8192x4096), reuses qkv+y
  bf16_t* vT     = xn;                                   // 16777216 B (4x16x64x2048), overlays xn

  // weights -> bf16 transposed
  transpose_cast<<<dim3(96, 32), 256, 0, stream>>>(w_attn, wTattn, 1024, 3072);
  transpose_cast<<<dim3(32, 32), 256, 0, stream>>>(w_proj, wTproj, 1024, 1024);
  transpose_cast<<<dim3(128, 32), 256, 0, stream>>>(w_fc, wTfc, 1024, 4096);
  transpose_cast<<<dim3(32, 128), 256, 0, stream>>>(w_fc2, wTfc2, 4096, 1024);

  // LN1 -> xn
  ln_kernel<<<8192, 256, 0, stream>>>(x, ln1g, ln1b, xn);
  // qkv = xn @ w_attn + b_attn   (bf16 out)
  gemm128<EPI_BF16><<<dim3(24, 32), 512, 0, stream>>>(xn, wTattn, b_attn, nullptr, qkv, 8192, 3072, 1024);
  // V -> V^T  (xn is dead now; vT overlays it)
  transpose_v<<<dim3(32, 16, 4), 256, 0, stream>>>(qkv, vT);
  // attention -> yb
  attn_kernel<<<dim3(1024), 256, 0, stream>>>(qkv, vT, yb);
  // x2 = x + yb @ w_proj + b_proj (fp32)
  gemm128<EPI_RESID><<<dim3(8, 32), 512, 0, stream>>>(yb, wTproj, b_proj, x, x2, 8192, 1024, 1024);
  // LN2 -> xn
  ln_kernel<<<8192, 256, 0, stream>>>(x2, ln2g, ln2b, xn);
  // hb = gelu(xn @ w_fc + b_fc)  (bf16)
  gemm256<EPI_GELU><<<dim3(16, 32), 512, 0, stream>>>(xn, wTfc, b_fc, nullptr, hb, 8192, 4096, 1024);
  // out = x2 + hb @ w_fc2 + b_fc2 (fp32)
  gemm128<EPI_RESID><<<dim3(8, 32), 512, 0, stream>>>(hb, wTfc2, b_fc2, x2, out, 8192, 1024, 4096);
}